// Round 3
// baseline (85.421 us; speedup 1.0000x reference)
//
#include <hip/hip_runtime.h>

// ArithmeticCompute: circle-encoded modular arithmetic over PRIMES.
// out[3][B*S][10][2] = {add, sub, mul} on the unit circle.
//
// Block = one 64-pair group x all 10 primes (640 threads, 10 waves).
// Wave w handles prime index w -> per-prime template dispatch stays
// wave-uniform (no intra-wave divergence).
// All global I/O is coalesced via LDS staging (the natural per-thread
// access is float2 at stride 80 B = a 64-line gather per wave; staged
// tiles turn 5 strided mem-instrs/thread into 5 coalesced ones).
// LDS rows padded to 21 floats -> per-thread gather is 2-way bank
// aliasing (free on gfx950, m136).

#define SOFTMAX_TEMP 1000.0f

constexpr double PI_D = 3.14159265358979323846264338327950288;

constexpr double tay_cos(double x) {
    double x2 = x * x, term = 1.0, sum = 1.0;
    for (int k = 1; k <= 15; ++k) { term *= -x2 / double((2 * k - 1) * (2 * k)); sum += term; }
    return sum;
}
constexpr double tay_sin(double x) {
    double x2 = x * x, term = x, sum = x;
    for (int k = 1; k <= 15; ++k) { term *= -x2 / double((2 * k) * (2 * k + 1)); sum += term; }
    return sum;
}

template <int P> struct Tab { float c[P]; float s[P]; };

template <int P>
constexpr Tab<P> make_tab() {
    Tab<P> t{};
    for (int r = 0; r < P; ++r) {
        double x = 2.0 * PI_D * double(r) / double(P);
        if (x > PI_D) x -= 2.0 * PI_D;
        t.c[r] = (float)tay_cos(x);
        t.s[r] = (float)tay_sin(x);
    }
    return t;
}

// mul on the circle: double soft-decode -> residue histogram -> re-encode.
// out = (sum_{i,j} ea[i]*eb[j]*tmpl[(i*j)%P]) / (Sa*Sb)
template <int P>
__device__ __forceinline__ void mul_prime(float ca, float sa, float cb, float sb,
                                          float& oc, float& os) {
    constexpr Tab<P> T = make_tab<P>();

    // Pass 1: maxes for both sides (nothing stored).
    float ma = -1e30f, mb = -1e30f;
#pragma unroll
    for (int r = 0; r < P; ++r) {
        ma = fmaxf(ma, ca * T.c[r] + sa * T.s[r]);
        mb = fmaxf(mb, cb * T.c[r] + sb * T.s[r]);
    }

    // Pass 2: b-side softmax numerators (stored) + sum.
    float eb[P];
    float Sb = 0.f;
#pragma unroll
    for (int r = 0; r < P; ++r) {
        float x = __expf(SOFTMAX_TEMP * (cb * T.c[r] + sb * T.s[r] - mb));
        eb[r] = x; Sb += x;
    }

    // Pass 3: residue histogram W[k] = sum_{(i*j)%P==k} ea[i]*eb[j].
    // ea recomputed on the fly; i=0 row and j=0 column folded in closed form.
    float W[P];
#pragma unroll
    for (int k = 0; k < P; ++k) W[k] = 0.f;

    float Sa = 0.f, ea0 = 0.f;
#pragma unroll
    for (int i = 0; i < P; ++i) {
        float ea_i = __expf(SOFTMAX_TEMP * (ca * T.c[i] + sa * T.s[i] - ma));
        Sa += ea_i;
        if (i == 0) { ea0 = ea_i; }
        else {
#pragma unroll
            for (int j = 1; j < P; ++j) {
                const int k = (i * j) % P;  // compile-time after unroll
                W[k] = fmaf(ea_i, eb[j], W[k]);
            }
        }
    }
    W[0] += ea0 * Sb + eb[0] * (Sa - ea0);

    float accC = 0.f, accS = 0.f;
#pragma unroll
    for (int k = 0; k < P; ++k) {
        accC = fmaf(W[k], T.c[k], accC);
        accS = fmaf(W[k], T.s[k], accS);
    }
    const float inv = 1.0f / (Sa * Sb);
    oc = accC * inv;
    os = accS * inv;
}

__global__ __launch_bounds__(640, 5) void arith_kernel(const float* __restrict__ a,
                                                       const float* __restrict__ b,
                                                       float* __restrict__ out,
                                                       int n_pairs) {
    // Padded tiles: 64 pairs x 21 floats (20 used). t2 only used for output.
    __shared__ float t0[64 * 21], t1[64 * 21], t2[64 * 21];

    const int t = threadIdx.x;   // 0..639
    const int gbase = blockIdx.x * 1280;  // group base, in floats

    // Phase 1: coalesced global -> padded LDS (a and b tiles).
    {
        const int e = 2 * t;                   // 0..1278, even
        const int pr = e / 20, off = e - pr * 20;
        const int la = pr * 21 + off;          // off <= 18, so off+1 same row
        const float2 av = *(const float2*)(a + gbase + e);
        const float2 bv = *(const float2*)(b + gbase + e);
        t0[la] = av.x; t0[la + 1] = av.y;
        t1[la] = bv.x; t1[la + 1] = bv.y;
    }
    __syncthreads();

    const int lane = t & 63;
    const int pi = t >> 6;                     // prime index, wave-uniform
    const int la = lane * 21 + pi * 2;
    const float ca = t0[la], sa = t0[la + 1];
    const float cb = t1[la], sb = t1[la + 1];
    __syncthreads();  // all phase-1 data consumed; tiles reusable for output

    // add: complex multiply a*b ; sub: a * conj(b).
    const float pcc = ca * cb, pss = sa * sb, psc = sa * cb, pcs = ca * sb;

    float oc, os;
    switch (pi) {
        case 0: mul_prime<2>(ca, sa, cb, sb, oc, os); break;
        case 1: mul_prime<3>(ca, sa, cb, sb, oc, os); break;
        case 2: mul_prime<5>(ca, sa, cb, sb, oc, os); break;
        case 3: mul_prime<7>(ca, sa, cb, sb, oc, os); break;
        case 4: mul_prime<11>(ca, sa, cb, sb, oc, os); break;
        case 5: mul_prime<13>(ca, sa, cb, sb, oc, os); break;
        case 6: mul_prime<17>(ca, sa, cb, sb, oc, os); break;
        case 7: mul_prime<19>(ca, sa, cb, sb, oc, os); break;
        case 8: mul_prime<23>(ca, sa, cb, sb, oc, os); break;
        default: mul_prime<29>(ca, sa, cb, sb, oc, os); break;
    }

    // Stage outputs (each thread writes only the slots it alone read).
    t0[la] = pcc - pss; t0[la + 1] = psc + pcs;   // add
    t1[la] = pcc + pss; t1[la + 1] = psc - pcs;   // sub
    t2[la] = oc;        t2[la + 1] = os;          // mul
    __syncthreads();

    // Phase 3: coalesced LDS -> global for all three planes.
    {
        const int e = 2 * t;
        const int pr = e / 20, off = e - pr * 20;
        const int ls = pr * 21 + off;
        const int plane = n_pairs * 20;
        *(float2*)(out + gbase + e)             = make_float2(t0[ls], t0[ls + 1]);
        *(float2*)(out + plane + gbase + e)     = make_float2(t1[ls], t1[ls + 1]);
        *(float2*)(out + 2 * plane + gbase + e) = make_float2(t2[ls], t2[ls + 1]);
    }
}

extern "C" void kernel_launch(void* const* d_in, const int* in_sizes, int n_in,
                              void* d_out, int out_size, void* d_ws, size_t ws_size,
                              hipStream_t stream) {
    const float* a = (const float*)d_in[0];
    const float* b = (const float*)d_in[1];
    float* out = (float*)d_out;
    const int n_pairs = in_sizes[0] / 20;   // B*S = 65536 (multiple of 64)
    const int n_groups = n_pairs / 64;      // 1024 blocks

    dim3 block(640);
    dim3 grid(n_groups);
    arith_kernel<<<grid, block, 0, stream>>>(a, b, out, n_pairs);
}

// Round 5
// 79.906 us; speedup vs baseline: 1.0690x; 1.0690x over previous
//
#include <hip/hip_runtime.h>

// ArithmeticCompute: circle-encoded modular arithmetic over PRIMES.
// out[3][B*S][10][2] = {add, sub, mul} on the unit circle.
//
// Block = one 64-pair group x all 10 primes (640 threads, 10 waves).
// Wave w handles prime index w -> per-prime template dispatch is
// wave-uniform (no intra-wave divergence).
//
// All global I/O is coalesced via LDS staging (direct strided access is
// a 64-line-per-wave gather and cost ~25-30 us in R1/R2). LDS tiles are
// native float2 arrays, row stride 11 float2 (64 pairs x 10 primes + pad):
// every LDS op is a naturally aligned ds_read_b64/ds_write_b64.
// Inputs (t0,t1) and outputs (o0,o1,o2) use DEDICATED buffers -> no slot
// is ever read and rewritten, only 2 barriers total.
//
// R3 lesson: do NOT set a min-occupancy floor in __launch_bounds__ - the
// hot loop needs ~75+ live VGPRs and (640,5) forced a 48-VGPR cap with
// catastrophic scratch spilling (VALUBusy 0.37%).

#define SOFTMAX_TEMP 1000.0f

constexpr double PI_D = 3.14159265358979323846264338327950288;

constexpr double tay_cos(double x) {
    double x2 = x * x, term = 1.0, sum = 1.0;
    for (int k = 1; k <= 15; ++k) { term *= -x2 / double((2 * k - 1) * (2 * k)); sum += term; }
    return sum;
}
constexpr double tay_sin(double x) {
    double x2 = x * x, term = x, sum = x;
    for (int k = 1; k <= 15; ++k) { term *= -x2 / double((2 * k) * (2 * k + 1)); sum += term; }
    return sum;
}

template <int P> struct Tab { float c[P]; float s[P]; };

template <int P>
constexpr Tab<P> make_tab() {
    Tab<P> t{};
    for (int r = 0; r < P; ++r) {
        double x = 2.0 * PI_D * double(r) / double(P);
        if (x > PI_D) x -= 2.0 * PI_D;
        t.c[r] = (float)tay_cos(x);
        t.s[r] = (float)tay_sin(x);
    }
    return t;
}

// mul on the circle: double soft-decode -> residue histogram -> re-encode.
// out = (sum_{i,j} ea[i]*eb[j]*tmpl[(i*j)%P]) / (Sa*Sb)
template <int P>
__device__ __forceinline__ void mul_prime(float ca, float sa, float cb, float sb,
                                          float& oc, float& os) {
    constexpr Tab<P> T = make_tab<P>();

    // Pass 1: maxes for both sides (nothing stored).
    float ma = -1e30f, mb = -1e30f;
#pragma unroll
    for (int r = 0; r < P; ++r) {
        ma = fmaxf(ma, ca * T.c[r] + sa * T.s[r]);
        mb = fmaxf(mb, cb * T.c[r] + sb * T.s[r]);
    }

    // Pass 2: b-side softmax numerators (stored) + sum.
    float eb[P];
    float Sb = 0.f;
#pragma unroll
    for (int r = 0; r < P; ++r) {
        float x = __expf(SOFTMAX_TEMP * (cb * T.c[r] + sb * T.s[r] - mb));
        eb[r] = x; Sb += x;
    }

    // Pass 3: residue histogram W[k] = sum_{(i*j)%P==k} ea[i]*eb[j].
    // ea recomputed on the fly; i=0 row and j=0 column folded in closed form.
    float W[P];
#pragma unroll
    for (int k = 0; k < P; ++k) W[k] = 0.f;

    float Sa = 0.f, ea0 = 0.f;
#pragma unroll
    for (int i = 0; i < P; ++i) {
        float ea_i = __expf(SOFTMAX_TEMP * (ca * T.c[i] + sa * T.s[i] - ma));
        Sa += ea_i;
        if (i == 0) { ea0 = ea_i; }
        else {
#pragma unroll
            for (int j = 1; j < P; ++j) {
                const int k = (i * j) % P;  // compile-time after unroll
                W[k] = fmaf(ea_i, eb[j], W[k]);
            }
        }
    }
    W[0] += ea0 * Sb + eb[0] * (Sa - ea0);

    float accC = 0.f, accS = 0.f;
#pragma unroll
    for (int k = 0; k < P; ++k) {
        accC = fmaf(W[k], T.c[k], accC);
        accS = fmaf(W[k], T.s[k], accS);
    }
    const float inv = 1.0f / (Sa * Sb);
    oc = accC * inv;
    os = accS * inv;
}

__global__ __launch_bounds__(640) void arith_kernel(const float* __restrict__ a,
                                                    const float* __restrict__ b,
                                                    float* __restrict__ out,
                                                    int n_pairs) {
    // float2 tiles: 64 rows (pairs) x 11 slots (10 primes + 1 pad).
    __shared__ float2 t0[64 * 11], t1[64 * 11];          // inputs a, b
    __shared__ float2 o0[64 * 11], o1[64 * 11], o2[64 * 11];  // add, sub, mul

    const int t = threadIdx.x;            // 0..639 == float2 index in tile
    const int pr = t / 10, of = t - pr * 10;  // row (pair), column (prime)
    const int li = pr * 11 + of;          // linear LDS slot for staging
    const int gf = blockIdx.x * 640 + t;  // global float2 index

    // Phase 1: coalesced global -> LDS.
    t0[li] = ((const float2*)a)[gf];
    t1[li] = ((const float2*)b)[gf];
    __syncthreads();

    // Phase 2: per-(pair, prime) compute. Wave pi handles prime pi.
    const int lane = t & 63;
    const int pi = t >> 6;                // wave-uniform
    const int lc = lane * 11 + pi;        // this thread's compute slot
    const float2 av = t0[lc];
    const float2 bv = t1[lc];
    const float ca = av.x, sa = av.y, cb = bv.x, sb = bv.y;

    // add: complex multiply a*b ; sub: a * conj(b).
    const float pcc = ca * cb, pss = sa * sb, psc = sa * cb, pcs = ca * sb;

    float oc, os;
    switch (pi) {
        case 0: mul_prime<2>(ca, sa, cb, sb, oc, os); break;
        case 1: mul_prime<3>(ca, sa, cb, sb, oc, os); break;
        case 2: mul_prime<5>(ca, sa, cb, sb, oc, os); break;
        case 3: mul_prime<7>(ca, sa, cb, sb, oc, os); break;
        case 4: mul_prime<11>(ca, sa, cb, sb, oc, os); break;
        case 5: mul_prime<13>(ca, sa, cb, sb, oc, os); break;
        case 6: mul_prime<17>(ca, sa, cb, sb, oc, os); break;
        case 7: mul_prime<19>(ca, sa, cb, sb, oc, os); break;
        case 8: mul_prime<23>(ca, sa, cb, sb, oc, os); break;
        default: mul_prime<29>(ca, sa, cb, sb, oc, os); break;
    }

    o0[lc] = make_float2(pcc - pss, psc + pcs);
    o1[lc] = make_float2(pcc + pss, psc - pcs);
    o2[lc] = make_float2(oc, os);
    __syncthreads();

    // Phase 3: coalesced LDS -> global, all three planes.
    const int planef2 = n_pairs * 10;     // plane size in float2
    float2* o = (float2*)out;
    o[gf]                = o0[li];
    o[planef2 + gf]      = o1[li];
    o[2 * planef2 + gf]  = o2[li];
}

extern "C" void kernel_launch(void* const* d_in, const int* in_sizes, int n_in,
                              void* d_out, int out_size, void* d_ws, size_t ws_size,
                              hipStream_t stream) {
    const float* a = (const float*)d_in[0];
    const float* b = (const float*)d_in[1];
    float* out = (float*)d_out;
    const int n_pairs = in_sizes[0] / 20;   // B*S = 65536 (multiple of 64)
    const int n_groups = n_pairs / 64;      // 1024 blocks

    dim3 block(640);
    dim3 grid(n_groups);
    arith_kernel<<<grid, block, 0, stream>>>(a, b, out, n_pairs);
}

// Round 6
// 75.448 us; speedup vs baseline: 1.1322x; 1.0591x over previous
//
#include <hip/hip_runtime.h>

// ArithmeticCompute: circle-encoded modular arithmetic over PRIMES.
// out[3][B*S][10][2] = {add, sub, mul} on the unit circle.
//
// Block = one 64-pair group x all 10 primes (640 threads, 10 waves).
// Wave w handles prime index w -> wave-uniform template dispatch.
// I/O staged through dedicated float2 LDS tiles (validated in R5).
//
// Quartet trick (R6): for odd p, pair residues i<->p-i, j<->p-j. With
// ua=ea_i+ea_{p-i}, va=ea_i-ea_{p-i} (same for b), each quartet updates
//   A[kr] = W[k]+W[p-k]  += ua*ub      (k = i*j mod p, kr = min(k,p-k))
//   B[kr] = W[k]-W[p-k]  +-= va*vb     (sign = free VOP3 neg modifier)
// and the output needs only sum(A*cos) (even) and sum(B*sin) (odd):
// the pair loop is (p-1)^2/2 FMAs instead of (p-1)^2, with ~half the
// live registers and half the code size.
//
// R3 lesson: no min-occupancy floor in __launch_bounds__ (forced 48-VGPR
// cap -> catastrophic scratch spill, VALUBusy 0.37%).

#define TEMP_LOG2E 1442.6950408889634f  // softmax_temperature * log2(e)

constexpr double PI_D = 3.14159265358979323846264338327950288;

constexpr double tay_cos(double x) {
    double x2 = x * x, term = 1.0, sum = 1.0;
    for (int k = 1; k <= 15; ++k) { term *= -x2 / double((2 * k - 1) * (2 * k)); sum += term; }
    return sum;
}
constexpr double tay_sin(double x) {
    double x2 = x * x, term = x, sum = x;
    for (int k = 1; k <= 15; ++k) { term *= -x2 / double((2 * k) * (2 * k + 1)); sum += term; }
    return sum;
}
constexpr double ang_red(int r, int P) {  // 2*pi*r/P reduced to [-pi, pi]
    double x = 2.0 * PI_D * double(r) / double(P);
    return (x > PI_D) ? x - 2.0 * PI_D : x;
}

// Scaled decode templates: KT*cos(2pi r/P), KT*sin(2pi r/P), r in [0,P).
template <int P> struct TabS { float c[P]; float s[P]; };
template <int P>
constexpr TabS<P> make_tabs() {
    TabS<P> t{};
    for (int r = 0; r < P; ++r) {
        t.c[r] = (float)(double(TEMP_LOG2E) * tay_cos(ang_red(r, P)));
        t.s[r] = (float)(double(TEMP_LOG2E) * tay_sin(ang_red(r, P)));
    }
    return t;
}
// Unscaled re-encode templates for the epilogue, k in [0, (P-1)/2].
template <int P> struct TabE { float c[P / 2 + 1]; float s[P / 2 + 1]; };
template <int P>
constexpr TabE<P> make_tabe() {
    TabE<P> t{};
    for (int k = 0; k <= P / 2; ++k) {
        t.c[k] = (float)tay_cos(ang_red(k, P));
        t.s[k] = (float)tay_sin(ang_red(k, P));
    }
    return t;
}

template <int P>
__device__ __forceinline__ void mul_prime(float ca, float sa, float cb, float sb,
                                          float& oc, float& os) {
    static_assert(P % 2 == 1, "generic path requires odd P");
    constexpr int H = (P - 1) / 2;
    constexpr TabS<P> T = make_tabs<P>();
    constexpr TabE<P> E = make_tabe<P>();

    // Pass 1: maxes of the scaled similarities (overflow guard).
    float ma = -1e30f, mb = -1e30f;
#pragma unroll
    for (int r = 0; r < P; ++r) {
        ma = fmaxf(ma, ca * T.c[r] + sa * T.s[r]);
        mb = fmaxf(mb, cb * T.c[r] + sb * T.s[r]);
    }

    // Pass 2: b-side folded softmax numerators.
    // eb_r = exp2(cb*T.c[r] + sb*T.s[r] - mb); store ub=eb_j+eb_{P-j},
    // vb=eb_j-eb_{P-j} for j in [1,H].
    float eb0 = __builtin_amdgcn_exp2f(cb * T.c[0] - mb);  // T.s[0] == 0
    float Sb = eb0;
    float ub[H], vb[H];
#pragma unroll
    for (int j = 1; j <= H; ++j) {
        float e1 = __builtin_amdgcn_exp2f(cb * T.c[j] + sb * T.s[j] - mb);
        float e2 = __builtin_amdgcn_exp2f(cb * T.c[P - j] + sb * T.s[P - j] - mb);
        Sb += e1 + e2;
        ub[j - 1] = e1 + e2;
        vb[j - 1] = e1 - e2;
    }

    // Pass 3: a-side outer loop (recomputed, nothing stored) + pair loop.
    float A[H], Bacc[H];
#pragma unroll
    for (int k = 0; k < H; ++k) { A[k] = 0.f; Bacc[k] = 0.f; }

    float ea0 = __builtin_amdgcn_exp2f(ca * T.c[0] - ma);
    float Sa = ea0;
#pragma unroll
    for (int i = 1; i <= H; ++i) {
        float f1 = __builtin_amdgcn_exp2f(ca * T.c[i] + sa * T.s[i] - ma);
        float f2 = __builtin_amdgcn_exp2f(ca * T.c[P - i] + sa * T.s[P - i] - ma);
        Sa += f1 + f2;
        const float ua = f1 + f2, va = f1 - f2;
#pragma unroll
        for (int j = 1; j <= H; ++j) {
            constexpr int dummy = 0; (void)dummy;
            const int k0 = (i * j) % P;            // compile-time after unroll
            const int kr = (k0 <= H) ? k0 : P - k0;
            A[kr - 1] = fmaf(ua, ub[j - 1], A[kr - 1]);
            if (k0 <= H) Bacc[kr - 1] = fmaf(va,  vb[j - 1], Bacc[kr - 1]);
            else         Bacc[kr - 1] = fmaf(-va, vb[j - 1], Bacc[kr - 1]);
        }
    }

    // Zero row/column: contributes only to W[0].
    const float W0 = ea0 * Sb + eb0 * (Sa - ea0);

    // Epilogue: re-encode. cos is even in k, sin is odd.
    float accC = W0, accS = 0.f;
#pragma unroll
    for (int k = 1; k <= H; ++k) {
        accC = fmaf(A[k - 1],    E.c[k], accC);
        accS = fmaf(Bacc[k - 1], E.s[k], accS);
    }
    const float inv = 1.0f / (Sa * Sb);
    oc = accC * inv;
    os = accS * inv;
}

// P = 2: closed form (templates are (1,0) and (-1,0); sin terms vanish).
template <>
__device__ __forceinline__ void mul_prime<2>(float ca, float sa, float cb, float sb,
                                             float& oc, float& os) {
    const float ka = ca * TEMP_LOG2E, kb = cb * TEMP_LOG2E;
    const float ma = fabsf(ka), mb = fabsf(kb);
    const float ea0 = __builtin_amdgcn_exp2f(ka - ma);
    const float ea1 = __builtin_amdgcn_exp2f(-ka - ma);
    const float eb0 = __builtin_amdgcn_exp2f(kb - mb);
    const float eb1 = __builtin_amdgcn_exp2f(-kb - mb);
    const float Sa = ea0 + ea1, Sb = eb0 + eb1;
    const float W0 = ea0 * Sb + eb0 * Sa - ea0 * eb0;  // (0,*),(*,0) pairs
    const float W1 = ea1 * eb1;
    oc = (W0 - W1) / (Sa * Sb);
    os = 0.f;
}

__global__ __launch_bounds__(640) void arith_kernel(const float* __restrict__ a,
                                                    const float* __restrict__ b,
                                                    float* __restrict__ out,
                                                    int n_pairs) {
    // float2 tiles: 64 rows (pairs) x 11 slots (10 primes + 1 pad).
    __shared__ float2 t0[64 * 11], t1[64 * 11];               // inputs a, b
    __shared__ float2 o0[64 * 11], o1[64 * 11], o2[64 * 11];  // add, sub, mul

    const int t = threadIdx.x;                // 0..639 == float2 index in tile
    const int pr = t / 10, of = t - pr * 10;  // row (pair), column (prime)
    const int li = pr * 11 + of;              // staging slot
    const int gf = blockIdx.x * 640 + t;      // global float2 index

    // Phase 1: coalesced global -> LDS.
    t0[li] = ((const float2*)a)[gf];
    t1[li] = ((const float2*)b)[gf];
    __syncthreads();

    // Phase 2: per-(pair, prime) compute. Wave pi handles prime pi.
    const int lane = t & 63;
    const int pi = t >> 6;                    // wave-uniform
    const int lc = lane * 11 + pi;
    const float2 av = t0[lc];
    const float2 bv = t1[lc];
    const float ca = av.x, sa = av.y, cb = bv.x, sb = bv.y;

    // add: complex multiply a*b ; sub: a * conj(b).
    const float pcc = ca * cb, pss = sa * sb, psc = sa * cb, pcs = ca * sb;

    float oc, os;
    switch (pi) {
        case 0: mul_prime<2>(ca, sa, cb, sb, oc, os); break;
        case 1: mul_prime<3>(ca, sa, cb, sb, oc, os); break;
        case 2: mul_prime<5>(ca, sa, cb, sb, oc, os); break;
        case 3: mul_prime<7>(ca, sa, cb, sb, oc, os); break;
        case 4: mul_prime<11>(ca, sa, cb, sb, oc, os); break;
        case 5: mul_prime<13>(ca, sa, cb, sb, oc, os); break;
        case 6: mul_prime<17>(ca, sa, cb, sb, oc, os); break;
        case 7: mul_prime<19>(ca, sa, cb, sb, oc, os); break;
        case 8: mul_prime<23>(ca, sa, cb, sb, oc, os); break;
        default: mul_prime<29>(ca, sa, cb, sb, oc, os); break;
    }

    o0[lc] = make_float2(pcc - pss, psc + pcs);
    o1[lc] = make_float2(pcc + pss, psc - pcs);
    o2[lc] = make_float2(oc, os);
    __syncthreads();

    // Phase 3: coalesced LDS -> global, all three planes.
    const int planef2 = n_pairs * 10;         // plane size in float2
    float2* o = (float2*)out;
    o[gf]               = o0[li];
    o[planef2 + gf]     = o1[li];
    o[2 * planef2 + gf] = o2[li];
}

extern "C" void kernel_launch(void* const* d_in, const int* in_sizes, int n_in,
                              void* d_out, int out_size, void* d_ws, size_t ws_size,
                              hipStream_t stream) {
    const float* a = (const float*)d_in[0];
    const float* b = (const float*)d_in[1];
    float* out = (float*)d_out;
    const int n_pairs = in_sizes[0] / 20;   // B*S = 65536 (multiple of 64)
    const int n_groups = n_pairs / 64;      // 1024 blocks

    dim3 block(640);
    dim3 grid(n_groups);
    arith_kernel<<<grid, block, 0, stream>>>(a, b, out, n_pairs);
}